// Round 16
// baseline (83.618 us; speedup 1.0000x reference)
//
#include <hip/hip_runtime.h>
#include <cfloat>

#define Bn 1024
#define Ln 200
#define En 128
#define An 128
#define Hn 4

// ---- ws layout (total 1974272 B; proven ws_size >= 2363392) ----
#define WS_POSW1   0                        // 208*128*4 = 106496 (pad rows zero)
#define WS_W1FRAG  106496                   // 2048 entries * 16B = 32768
#define WS_ATTPOOL 139264                   // 1024 slots * SLOT (pooled bf16[512])
#define SLOT       1664
#define WS_WOUTT   1843200                  // 128*512 bf16 = 131072
#define WS_NEEDED  1974272

using f32x4  = __attribute__((ext_vector_type(4))) float;
using bf16x8 = __attribute__((ext_vector_type(8))) short;

__device__ __forceinline__ unsigned short f2bf(float f){
    unsigned u = __builtin_bit_cast(unsigned, f);
    u = (u + 0x7FFFu + ((u >> 16) & 1u)) >> 16;   // RNE
    return (unsigned short)u;
}
__device__ __forceinline__ float bf2f(unsigned short s){
    unsigned u = ((unsigned)s) << 16;
    return __builtin_bit_cast(float, u);
}
// 5-inst tanh
__device__ __forceinline__ float tanh_cheap(float x){
    float e = __expf(2.f * x);
    float r = __builtin_amdgcn_rcpf(e + 1.f);
    return fmaf(-2.f, r, 1.f);
}
// legacy (fallback kernel only)
__device__ __forceinline__ float tanh_fast(float x){
    x = fminf(fmaxf(x, -12.f), 12.f);
    float e = __expf(2.f * x);
    return 1.f - 2.f / (e + 1.f);
}
// pack 2 f32 -> 2 bf16 (RNE), single instruction
__device__ __forceinline__ unsigned cvt_pk_bf16(float lo, float hi){
    unsigned r;
    asm("v_cvt_pk_bf16_f32 %0, %1, %2" : "=v"(r) : "v"(lo), "v"(hi));
    return r;
}
// swizzled short-index for a [row][128] bf16 LDS array (256B rows, 16B granule XOR)
__device__ __forceinline__ int swz(int row, int k){
    return row * 128 + ((((k >> 3) ^ (row & 15)) << 3) | (k & 7));
}

// ================= prep: posW1 (f32), W1 fragments, Wout^T ==========================
// W1FRAG layout: entry E = (A*64 + lane)*4 + ks  (A = a-tile 0..7), 16B each.
__global__ __launch_bounds__(256) void sap_prep(
    const float* __restrict__ pos, const float* __restrict__ W1,
    const float* __restrict__ Wout, void* __restrict__ ws)
{
    const int t = threadIdx.x, blk = blockIdx.x;
    if (blk < 104){                       // posW1[l][a]; pad rows 0
        float* posW1 = (float*)((char*)ws + WS_POSW1);
        int l = blk * 2 + (t >> 7), a = t & 127;
        float acc = 0.f;
        if (l < Ln){
            #pragma unroll 4
            for (int k = 0; k < 128; ++k)
                acc += pos[l * En + k] * W1[k * An + a];
        }
        posW1[l * An + a] = acc;
    } else if (blk < 106){                // W1 fragments
        unsigned short* w1f = (unsigned short*)((char*)ws + WS_W1FRAG);
        int s = (blk - 104) * 256 + t;    // 0..511 = A*64 + lane
        int lane = s & 63;
        int A = s >> 6;
        int c = lane & 15, q = lane >> 4;
        #pragma unroll
        for (int ks = 0; ks < 4; ++ks){
            unsigned short v[8];
            #pragma unroll
            for (int j = 0; j < 8; ++j)
                v[j] = f2bf(W1[(ks * 32 + q * 8 + j) * An + A * 16 + c]);
            *(bf16x8*)&w1f[(s * 4 + ks) * 8] = *(bf16x8*)v;
        }
    } else {                              // WoutT[e][k] bf16
        unsigned short* wt = (unsigned short*)((char*)ws + WS_WOUTT);
        int flat = ((blk - 106) * 256 + t) * 4;   // e*512+k
        int e = flat >> 9, k = flat & 511;
        unsigned short v[4];
        #pragma unroll
        for (int i = 0; i < 4; ++i)
            v[i] = f2bf(Wout[(size_t)(k + i) * En + e]);
        *(uint2*)&wt[flat] = *(uint2*)v;
    }
}

// ================= MAIN: single-barrier-per-chunk att + softmax + pooling ===========
// 1024 blocks x 512 thr (8 waves). Double-buffered s_x in the 32 KB overlay
// (s_scr overlays both at pool time). Per chunk: prefetch(c+1) || MFMA(c) with
// direct ds_add_f32 into s_att4; convert+store(c+1); ONE barrier. 7 barriers total.
__global__ __launch_bounds__(512, 4) void sap_att11(
    const float* __restrict__ inp, const void* __restrict__ maskp,
    const float* __restrict__ W2, void* __restrict__ ws)
{
    __shared__ __align__(16) char smem_u[32768];   // overlay: 2x16 KB s_x | 32 KB s_scr
    __shared__ float s_att4[208 * 4];              // 3.3 KB [l][h] f32 (persistent)
    __shared__ float s_mask[256];                  // 1 KB (persistent)

    float (*s_scr)[512] = (float (*)[512])smem_u;  // pool-phase view

    const int t = threadIdx.x, lane = t & 63, w = t >> 6;
    const int c = lane & 15, q = lane >> 4;
    const int b = blockIdx.x;

    const unsigned short* w1f   = (const unsigned short*)((char*)ws + WS_W1FRAG);
    const float*          posW1 = (const float*)((char*)ws + WS_POSW1);
    unsigned short*       slot  = (unsigned short*)((char*)ws + WS_ATTPOOL + (size_t)b * SLOT);
    const float4*         in4   = (const float4*)(inp + (size_t)b * (Ln * En));

    // A-fragments (once per block, pinned) + W2 rows
    bf16x8 af[4];
    #pragma unroll
    for (int ks = 0; ks < 4; ++ks)
        af[ks] = *(const bf16x8*)&w1f[((w * 64 + lane) * 4 + ks) * 8];
    float4 w2a[4];
    #pragma unroll
    for (int v = 0; v < 4; ++v)
        w2a[v] = *(const float4*)&W2[(w * 16 + q * 4 + v) * Hn];

    // zero att accumulators
    for (int i = t; i < 832; i += 512) s_att4[i] = 0.f;

    // mask dtype detect (per-wave) + stage mask
    {
        unsigned word = ((const unsigned*)maskp)[lane];
        unsigned long long bi  = __ballot(word > 1u);
        unsigned long long bfm = __ballot(word != 0u && word != 0x3F800000u);
        int flag = (bi == 0ull) ? 0 : ((bfm == 0ull) ? 2 : 1);
        if (t < 256){
            float m = 0.f;
            if (t < Ln){
                int mv;
                if (flag == 0)      mv = ((const int*)maskp)[b * Ln + t] != 0;
                else if (flag == 1) mv = ((const unsigned char*)maskp)[b * Ln + t] != 0;
                else                mv = ((const float*)maskp)[b * Ln + t] != 0.f;
                m = mv ? 1.f : 0.f;
            }
            s_mask[t] = m;
        }
    }

    // staging helper views
    #define SXBUF(i) ((unsigned short*)(smem_u + (i) * 16384))
    #define PUTV(sx, vi, idx) { int ll = (idx) >> 5, kk = ((idx) & 31) * 4;            \
        uint2 val = make_uint2(cvt_pk_bf16(vi.x, vi.y), cvt_pk_bf16(vi.z, vi.w));      \
        *(uint2*)&(sx)[swz(ll, kk)] = val; }

    // ---- prologue: stage chunk 0 into buffer 0 (straight-line) ----
    {
        unsigned short* sx = SXBUF(0);
        float4 u0 = in4[t], u1 = in4[t + 512], u2 = in4[t + 1024], u3 = in4[t + 1536];
        PUTV(sx, u0, t) PUTV(sx, u1, t + 512) PUTV(sx, u2, t + 1024) PUTV(sx, u3, t + 1536)
    }
    __syncthreads();                                   // B0: zeros, mask, chunk0 ready

    for (int cch = 0; cch < 4; ++cch){
        const int cur = cch & 1;
        const int NT = (cch < 3) ? 4 : 1;
        unsigned short* s_x = SXBUF(cur);

        // ---- issue prefetch loads for chunk cch+1 (latency hides under MFMA) ----
        const int nxt = cch + 1;
        float4 u0 = make_float4(0.f,0.f,0.f,0.f), u1 = u0, u2 = u0, u3 = u0;
        if (nxt < 3){
            const int base = nxt * 2048;
            u0 = in4[base + t];        u1 = in4[base + t + 512];
            u2 = in4[base + t + 1024]; u3 = in4[base + t + 1536];
        } else if (nxt == 3){
            if (t < 256) u0 = in4[3 * 2048 + t];       // 8 valid rows
        }

        // ---- MFMA (C-init = posW1) -> tanh -> dot W2 -> reduce -> ds_add_f32 ----
        for (int lt = 0; lt < NT; ++lt){
            int brow = lt * 16 + c;
            bf16x8 bfr[4];
            #pragma unroll
            for (int ks = 0; ks < 4; ++ks){
                int g = (ks * 4 + q) ^ c;
                bfr[ks] = *(bf16x8*)&s_x[brow * 128 + (g << 3)];
            }
            f32x4 acc = *(const f32x4*)&posW1[(size_t)(cch * 64 + brow) * An + w * 16 + q * 4];
            #pragma unroll
            for (int ks = 0; ks < 4; ++ks)
                acc = __builtin_amdgcn_mfma_f32_16x16x32_bf16(af[ks], bfr[ks], acc, 0, 0, 0);
            float contrib[4] = {0.f, 0.f, 0.f, 0.f};
            #pragma unroll
            for (int v = 0; v < 4; ++v){
                float hv = tanh_cheap(acc[v]);
                contrib[0] += hv * w2a[v].x;
                contrib[1] += hv * w2a[v].y;
                contrib[2] += hv * w2a[v].z;
                contrib[3] += hv * w2a[v].w;
            }
            #pragma unroll
            for (int h = 0; h < 4; ++h){
                contrib[h] += __shfl_xor(contrib[h], 16, 64);
                contrib[h] += __shfl_xor(contrib[h], 32, 64);
            }
            int gl = cch * 64 + brow;
            if (gl < Ln)
                atomicAdd(&s_att4[gl * 4 + q], contrib[q]);   // lane (c,q): head q
        }

        // ---- convert + store prefetched chunk into the other buffer ----
        if (nxt < 4){
            unsigned short* s_n = SXBUF(cur ^ 1);
            if (nxt < 3){
                PUTV(s_n, u0, t) PUTV(s_n, u1, t + 512)
                PUTV(s_n, u2, t + 1024) PUTV(s_n, u3, t + 1536)
            } else {
                uint2 val = make_uint2(0u, 0u);
                if (t < 256)
                    val = make_uint2(cvt_pk_bf16(u0.x, u0.y), cvt_pk_bf16(u0.z, u0.w));
                int ll = t >> 5, kk = (t & 31) * 4;   // rows 0..15 (8..15 zeroed)
                *(uint2*)&s_n[swz(ll, kk)] = val;
            }
        }
        __syncthreads();                               // one barrier per chunk
    }
    #undef PUTV
    #undef SXBUF

    // ---- softmax over l (waves 0-3, one per head); mask applied here ----
    if (t < 256){
        const int h = t >> 6, sl = t & 63;
        float v[4]; float mx = -FLT_MAX;
        #pragma unroll
        for (int i = 0; i < 4; ++i){
            int l = sl + i * 64;
            v[i] = (l < Ln) ? ((s_mask[l] > 0.5f) ? s_att4[l * 4 + h] : -1.0e30f)
                            : -3.0e38f;
            mx = fmaxf(mx, v[i]);
        }
        for (int s = 32; s; s >>= 1) mx = fmaxf(mx, __shfl_xor(mx, s, 64));
        float e[4]; float sum = 0.f;
        #pragma unroll
        for (int i = 0; i < 4; ++i){
            int l = sl + i * 64;
            e[i] = (l < Ln) ? __expf(v[i] - mx) : 0.f;
            sum += e[i];
        }
        for (int s = 32; s; s >>= 1) sum += __shfl_xor(sum, s, 64);
        float inv = 1.f / sum;
        #pragma unroll
        for (int i = 0; i < 4; ++i){
            int l = sl + i * 64;
            if (l < Ln) s_att4[l * 4 + h] = e[i] * inv;
        }
    }
    __syncthreads();     // chunk-phase views dead; s_scr live from here

    // ---- pooling: stream input (L2/L3-hot), 16 row-groups into overlaid s_scr ----
    {
        const int eg = t & 31, r = t >> 5;       // r = 0..15
        const float* xin = inp + (size_t)b * (Ln * En);
        f32x4 a0 = {0.f,0.f,0.f,0.f}, a1 = a0, a2 = a0, a3 = a0;
        for (int i = 0; i < 13; ++i){
            int l = i * 16 + r;
            if (l < Ln){
                f32x4 xv = *(const f32x4*)&xin[l * En + eg * 4];
                f32x4 w4 = *(const f32x4*)&s_att4[l * 4];
                a0 += xv * w4[0];
                a1 += xv * w4[1];
                a2 += xv * w4[2];
                a3 += xv * w4[3];
            }
        }
        *(f32x4*)&s_scr[r][0 * 128 + eg * 4] = a0;
        *(f32x4*)&s_scr[r][1 * 128 + eg * 4] = a1;
        *(f32x4*)&s_scr[r][2 * 128 + eg * 4] = a2;
        *(f32x4*)&s_scr[r][3 * 128 + eg * 4] = a3;
    }
    __syncthreads();

    // ---- final reduce over 16 row-groups -> pooled bf16 (flat h*128+e) ----
    {
        float sum = 0.f;
        #pragma unroll
        for (int r2 = 0; r2 < 16; ++r2) sum += s_scr[r2][t];
        slot[t] = f2bf(sum);
    }
}

// ================= K3: out = pooled @ Wout (MFMA) ===================================
__global__ __launch_bounds__(256) void sap_out(
    const void* __restrict__ ws, float* __restrict__ out)
{
    const unsigned short* wt = (const unsigned short*)((const char*)ws + WS_WOUTT);
    const int t = threadIdx.x, lane = t & 63, w = t >> 6;
    const int c = lane & 15, q = lane >> 4;
    const int b0 = blockIdx.x * 16;
    const int e0 = (blockIdx.y * 4 + w) * 16;

    const unsigned short* pslot =
        (const unsigned short*)((const char*)ws + WS_ATTPOOL + (size_t)(b0 + c) * SLOT);

    f32x4 acc = {0.f, 0.f, 0.f, 0.f};
    #pragma unroll 4
    for (int ks = 0; ks < 16; ++ks){
        bf16x8 afr = *(const bf16x8*)&pslot[ks * 32 + q * 8];
        bf16x8 bfr = *(const bf16x8*)&wt[(e0 + c) * 512 + ks * 32 + q * 8];
        acc = __builtin_amdgcn_mfma_f32_16x16x32_bf16(afr, bfr, acc, 0, 0, 0);
    }
    #pragma unroll
    for (int v = 0; v < 4; ++v)
        out[(size_t)(b0 + q * 4 + v) * En + e0 + c] = acc[v];
}

// ================= fallback (round-2 monolith) if ws ever shrinks ===================
__global__ __launch_bounds__(512, 4) void sap_fused_v2(
    const float* __restrict__ inp, const void* __restrict__ maskp,
    const float* __restrict__ pos, const float* __restrict__ W1,
    const float* __restrict__ W2, const float* __restrict__ Wout,
    float* __restrict__ out)
{
#define LP 208
    __shared__ unsigned short s_xp [LP * 128];
    __shared__ float s_att [4 * LP];
    __shared__ float s_mask[LP];
    __shared__ float s_pool[512];
    __shared__ float s_red [512];
    __shared__ int   s_flag;

    const int t = threadIdx.x;
    const int b = blockIdx.x;
    const int lane = t & 63, w = t >> 6;
    const int c = lane & 15, q = lane >> 4;

    if (t == 0){
        const unsigned* mw = (const unsigned*)maskp;
        int fi = 1, ff = 1;
        for (int i = 0; i < 64; ++i){
            unsigned word = mw[i];
            if (word > 1u) fi = 0;
            if (word != 0u && word != 0x3F800000u) ff = 0;
        }
        s_flag = fi ? 0 : (ff ? 2 : 1);
    }
    bf16x8 af[4];
    {
        const int arow = w * 16 + c;
        #pragma unroll
        for (int ks = 0; ks < 4; ++ks)
            #pragma unroll
            for (int j = 0; j < 8; ++j)
                af[ks][j] = (short)f2bf(W1[(ks * 32 + q * 8 + j) * An + arow]);
    }
    float w2a[4][4];
    #pragma unroll
    for (int v = 0; v < 4; ++v){
        float4 wv = *(const float4*)&W2[(w * 16 + q * 4 + v) * Hn];
        w2a[v][0] = wv.x; w2a[v][1] = wv.y; w2a[v][2] = wv.z; w2a[v][3] = wv.w;
    }
    __syncthreads();
    const int flag = s_flag;
    for (int l = t; l < LP; l += 512){
        float m = 0.f;
        if (l < Ln){
            int mv;
            if (flag == 0)      mv = ((const int*)maskp)[b * Ln + l] != 0;
            else if (flag == 1) mv = ((const unsigned char*)maskp)[b * Ln + l] != 0;
            else                mv = ((const float*)maskp)[b * Ln + l] != 0.f;
            m = mv ? 1.f : 0.f;
        }
        s_mask[l] = m;
    }
    for (int i = t; i < 4 * LP; i += 512) s_att[i] = 0.f;
    __syncthreads();
    {
        const float4* in4 = (const float4*)(inp + (size_t)b * (Ln * En));
        const float4* p4  = (const float4*)pos;
        #pragma unroll
        for (int it = 0; it < 13; ++it){
            int idx = it * 512 + t;
            int l = idx >> 5;
            int k = (idx & 31) * 4;
            uint2 val;
            if (idx < 6400){
                float m = s_mask[l];
                float4 a = in4[idx];
                float4 p = p4[idx];
                val = make_uint2((unsigned)f2bf(a.x*m+p.x) | ((unsigned)f2bf(a.y*m+p.y) << 16),
                                 (unsigned)f2bf(a.z*m+p.z) | ((unsigned)f2bf(a.w*m+p.w) << 16));
            } else val = make_uint2(0u, 0u);
            *(uint2*)&s_xp[swz(l, k)] = val;
        }
    }
    __syncthreads();
    for (int lt = 0; lt < 13; ++lt){
        int brow = lt * 16 + c;
        bf16x8 bfr[4];
        #pragma unroll
        for (int ks = 0; ks < 4; ++ks){
            int g = (ks * 4 + q) ^ c;
            bfr[ks] = *(bf16x8*)&s_xp[brow * 128 + (g << 3)];
        }
        f32x4 acc = {0.f, 0.f, 0.f, 0.f};
        #pragma unroll
        for (int ks = 0; ks < 4; ++ks)
            acc = __builtin_amdgcn_mfma_f32_16x16x32_bf16(af[ks], bfr[ks], acc, 0, 0, 0);
        float hv[4];
        #pragma unroll
        for (int v = 0; v < 4; ++v) hv[v] = tanh_fast(acc[v]);
        #pragma unroll
        for (int h = 0; h < 4; ++h){
            float contrib = hv[0]*w2a[0][h] + hv[1]*w2a[1][h] + hv[2]*w2a[2][h] + hv[3]*w2a[3][h];
            contrib += __shfl_xor(contrib, 16, 64);
            contrib += __shfl_xor(contrib, 32, 64);
            if (lane < 16) atomicAdd(&s_att[h * LP + lt * 16 + lane], contrib);
        }
    }
    __syncthreads();
    if (t < 256){
        const int sl = t & 63, h = t >> 6;
        float v[4]; bool ok[4]; float mx = -FLT_MAX;
        #pragma unroll
        for (int i = 0; i < 4; ++i){
            int l = sl + i * 64;
            ok[i] = (l < Ln) && (s_mask[l] > 0.5f);
            v[i]  = ok[i] ? s_att[h * LP + l] : -FLT_MAX;
            mx = fmaxf(mx, v[i]);
        }
        for (int s = 32; s; s >>= 1) mx = fmaxf(mx, __shfl_xor(mx, s, 64));
        float e[4]; float sum = 0.f;
        #pragma unroll
        for (int i = 0; i < 4; ++i){ e[i] = ok[i] ? __expf(v[i]-mx) : 0.f; sum += e[i]; }
        for (int s = 32; s; s >>= 1) sum += __shfl_xor(sum, s, 64);
        float inv = 1.f / sum;
        #pragma unroll
        for (int i = 0; i < 4; ++i){ int l = sl + i*64; if (l < LP) s_att[h*LP+l] = e[i]*inv; }
    }
    __syncthreads();
    {
        int h = t >> 7, e = t & 127;
        float acc = 0.f;
        #pragma unroll 4
        for (int l = 0; l < Ln; ++l){
            float xv = bf2f(s_xp[swz(l, e)]) - pos[l * En + e];
            acc += s_att[h * LP + l] * xv;
        }
        s_pool[h * En + e] = acc;
    }
    __syncthreads();
    {
        int qt = t >> 7, e = t & 127;
        float acc = 0.f;
        const float* wo = Wout + (size_t)(qt * 128) * En + e;
        #pragma unroll 4
        for (int i = 0; i < 128; ++i)
            acc += s_pool[qt * 128 + i] * wo[(size_t)i * En];
        s_red[t] = acc;
    }
    __syncthreads();
    if (t < 128)
        out[(size_t)b * En + t] = s_red[t] + s_red[t + 128] + s_red[t + 256] + s_red[t + 384];
#undef LP
}

extern "C" void kernel_launch(void* const* d_in, const int* in_sizes, int n_in,
                              void* d_out, int out_size, void* d_ws, size_t ws_size,
                              hipStream_t stream)
{
    const float* inp  = (const float*)d_in[0];
    const void*  mask = d_in[1];
    const float* pos  = (const float*)d_in[2];
    const float* W1   = (const float*)d_in[3];
    const float* W2   = (const float*)d_in[4];
    const float* Wout = (const float*)d_in[5];
    float* out = (float*)d_out;

    if (ws_size >= WS_NEEDED){
        sap_prep<<<170, 256, 0, stream>>>(pos, W1, Wout, d_ws);
        sap_att11<<<Bn, 512, 0, stream>>>(inp, mask, W2, d_ws);
        sap_out<<<dim3(64, 2), 256, 0, stream>>>(d_ws, out);
    } else {
        sap_fused_v2<<<Bn, 512, 0, stream>>>(inp, mask, pos, W1, W2, Wout, out);
    }
}

// Round 18
// 64.226 us; speedup vs baseline: 1.3019x; 1.3019x over previous
//
#include <hip/hip_runtime.h>
#include <cfloat>

#define Bn 1024
#define Ln 200
#define En 128
#define An 128
#define Hn 4

// ---- ws layout (total 1974272 B; proven ws_size >= 2363392) ----
#define WS_POSW1   0                        // 208*128*4 = 106496 (pad rows zero)
#define WS_W1FRAG  106496                   // 2048 entries * 16B = 32768
#define WS_ATTPOOL 139264                   // 1024 slots * SLOT (pooled bf16[512])
#define SLOT       1664
#define WS_WOUTT   1843200                  // 128*512 bf16 = 131072
#define WS_NEEDED  1974272

using f32x4  = __attribute__((ext_vector_type(4))) float;
using bf16x8 = __attribute__((ext_vector_type(8))) short;

__device__ __forceinline__ unsigned short f2bf(float f){
    unsigned u = __builtin_bit_cast(unsigned, f);
    u = (u + 0x7FFFu + ((u >> 16) & 1u)) >> 16;   // RNE
    return (unsigned short)u;
}
__device__ __forceinline__ float bf2f(unsigned short s){
    unsigned u = ((unsigned)s) << 16;
    return __builtin_bit_cast(float, u);
}
// 5-inst tanh
__device__ __forceinline__ float tanh_cheap(float x){
    float e = __expf(2.f * x);
    float r = __builtin_amdgcn_rcpf(e + 1.f);
    return fmaf(-2.f, r, 1.f);
}
// legacy (fallback kernel only)
__device__ __forceinline__ float tanh_fast(float x){
    x = fminf(fmaxf(x, -12.f), 12.f);
    float e = __expf(2.f * x);
    return 1.f - 2.f / (e + 1.f);
}
// pack 2 f32 -> 2 bf16 (RNE), single instruction
__device__ __forceinline__ unsigned cvt_pk_bf16(float lo, float hi){
    unsigned r;
    asm("v_cvt_pk_bf16_f32 %0, %1, %2" : "=v"(r) : "v"(lo), "v"(hi));
    return r;
}
// swizzled short-index for a [row][128] bf16 LDS array (256B rows, 16B granule XOR)
__device__ __forceinline__ int swz(int row, int k){
    return row * 128 + ((((k >> 3) ^ (row & 15)) << 3) | (k & 7));
}

// ================= prep: posW1 (f32), W1 fragments, Wout^T ==========================
// W1FRAG layout: entry E = (A*64 + lane)*4 + ks  (A = a-tile 0..7), 16B each.
__global__ __launch_bounds__(256) void sap_prep(
    const float* __restrict__ pos, const float* __restrict__ W1,
    const float* __restrict__ Wout, void* __restrict__ ws)
{
    const int t = threadIdx.x, blk = blockIdx.x;
    if (blk < 104){                       // posW1[l][a]; pad rows 0
        float* posW1 = (float*)((char*)ws + WS_POSW1);
        int l = blk * 2 + (t >> 7), a = t & 127;
        float acc = 0.f;
        if (l < Ln){
            #pragma unroll 4
            for (int k = 0; k < 128; ++k)
                acc += pos[l * En + k] * W1[k * An + a];
        }
        posW1[l * An + a] = acc;
    } else if (blk < 106){                // W1 fragments
        unsigned short* w1f = (unsigned short*)((char*)ws + WS_W1FRAG);
        int s = (blk - 104) * 256 + t;    // 0..511 = A*64 + lane
        int lane = s & 63;
        int A = s >> 6;
        int c = lane & 15, q = lane >> 4;
        #pragma unroll
        for (int ks = 0; ks < 4; ++ks){
            unsigned short v[8];
            #pragma unroll
            for (int j = 0; j < 8; ++j)
                v[j] = f2bf(W1[(ks * 32 + q * 8 + j) * An + A * 16 + c]);
            *(bf16x8*)&w1f[(s * 4 + ks) * 8] = *(bf16x8*)v;
        }
    } else {                              // WoutT[e][k] bf16
        unsigned short* wt = (unsigned short*)((char*)ws + WS_WOUTT);
        int flat = ((blk - 106) * 256 + t) * 4;   // e*512+k
        int e = flat >> 9, k = flat & 511;
        unsigned short v[4];
        #pragma unroll
        for (int i = 0; i < 4; ++i)
            v[i] = f2bf(Wout[(size_t)(k + i) * En + e]);
        *(uint2*)&wt[flat] = *(uint2*)v;
    }
}

// ================= MAIN: att7 + LDS overlay (round-15 proven version) ===============
// 1024 blocks x 512 thr (8 waves). s_scr[16][512] (pool phase only) overlays
// {s_x, s_part} (chunk phase only). Total LDS ~36.3 KB. Launch bounds (512,4).
__global__ __launch_bounds__(512, 4) void sap_att10(
    const float* __restrict__ inp, const void* __restrict__ maskp,
    const float* __restrict__ W2, void* __restrict__ ws)
{
    __shared__ __align__(16) char smem_u[32768];   // overlay region
    __shared__ float s_att4[208 * 4];              // 3.3 KB [l][h] f32 (persistent)
    __shared__ float s_mask[256];                  // 1 KB (persistent)

    unsigned short* s_x = (unsigned short*)smem_u;                   // 16 KB (chunk)
    float (*s_part)[4][64] = (float (*)[4][64])(smem_u + 16384);     // 8 KB (chunk)
    float (*s_scr)[512]    = (float (*)[512])smem_u;                 // 32 KB (pool)

    const int t = threadIdx.x, lane = t & 63, w = t >> 6;
    const int c = lane & 15, q = lane >> 4;
    const int b = blockIdx.x;

    const unsigned short* w1f   = (const unsigned short*)((char*)ws + WS_W1FRAG);
    const float*          posW1 = (const float*)((char*)ws + WS_POSW1);
    unsigned short*       slot  = (unsigned short*)((char*)ws + WS_ATTPOOL + (size_t)b * SLOT);

    // A-fragments (once per block, pinned) + W2 rows
    bf16x8 af[4];
    #pragma unroll
    for (int ks = 0; ks < 4; ++ks)
        af[ks] = *(const bf16x8*)&w1f[((w * 64 + lane) * 4 + ks) * 8];
    float4 w2a[4];
    #pragma unroll
    for (int v = 0; v < 4; ++v)
        w2a[v] = *(const float4*)&W2[(w * 16 + q * 4 + v) * Hn];

    // mask dtype detect (per-wave) + stage mask
    {
        unsigned word = ((const unsigned*)maskp)[lane];
        unsigned long long bi  = __ballot(word > 1u);
        unsigned long long bfm = __ballot(word != 0u && word != 0x3F800000u);
        int flag = (bi == 0ull) ? 0 : ((bfm == 0ull) ? 2 : 1);
        if (t < 256){
            float m = 0.f;
            if (t < Ln){
                int mv;
                if (flag == 0)      mv = ((const int*)maskp)[b * Ln + t] != 0;
                else if (flag == 1) mv = ((const unsigned char*)maskp)[b * Ln + t] != 0;
                else                mv = ((const float*)maskp)[b * Ln + t] != 0.f;
                m = mv ? 1.f : 0.f;
            }
            s_mask[t] = m;
        }
    }

    for (int cch = 0; cch < 4; ++cch){
        const int NT = (cch < 3) ? 4 : 1;

        // ---- stage chunk (straight-line, zero liveness across barrier) ----
        {
            const float4* in4 = (const float4*)(inp + (size_t)b * (Ln * En) + cch * 64 * En);
            #define PUTV(vi, idx) { int ll = (idx) >> 5, kk = ((idx) & 31) * 4;            \
                uint2 val = make_uint2(cvt_pk_bf16(vi.x, vi.y), cvt_pk_bf16(vi.z, vi.w));  \
                *(uint2*)&s_x[swz(ll, kk)] = val; }
            if (cch < 3){
                float4 u0 = in4[t], u1 = in4[t + 512], u2 = in4[t + 1024], u3 = in4[t + 1536];
                PUTV(u0, t) PUTV(u1, t + 512) PUTV(u2, t + 1024) PUTV(u3, t + 1536)
            } else {
                uint2 val = make_uint2(0u, 0u);
                if (t < 256){                  // 8 valid rows = 256 float4 slots
                    float4 u0 = in4[t];
                    val = make_uint2(cvt_pk_bf16(u0.x, u0.y), cvt_pk_bf16(u0.z, u0.w));
                }
                int ll = t >> 5, kk = (t & 31) * 4;   // rows 0..15 covered (8..15 zeroed)
                *(uint2*)&s_x[swz(ll, kk)] = val;
            }
            #undef PUTV
        }
        __syncthreads();                                     // B1

        // ---- MFMA (C-init = posW1) -> tanh -> dot W2 -> wave reduce -> s_part ----
        for (int lt = 0; lt < NT; ++lt){
            int brow = lt * 16 + c;
            bf16x8 bfr[4];
            #pragma unroll
            for (int ks = 0; ks < 4; ++ks){
                int g = (ks * 4 + q) ^ c;
                bfr[ks] = *(bf16x8*)&s_x[brow * 128 + (g << 3)];
            }
            f32x4 acc = *(const f32x4*)&posW1[(size_t)(cch * 64 + brow) * An + w * 16 + q * 4];
            #pragma unroll
            for (int ks = 0; ks < 4; ++ks)
                acc = __builtin_amdgcn_mfma_f32_16x16x32_bf16(af[ks], bfr[ks], acc, 0, 0, 0);
            float contrib[4] = {0.f, 0.f, 0.f, 0.f};
            #pragma unroll
            for (int v = 0; v < 4; ++v){
                float hv = tanh_cheap(acc[v]);
                contrib[0] += hv * w2a[v].x;
                contrib[1] += hv * w2a[v].y;
                contrib[2] += hv * w2a[v].z;
                contrib[3] += hv * w2a[v].w;
            }
            #pragma unroll
            for (int h = 0; h < 4; ++h){
                contrib[h] += __shfl_xor(contrib[h], 16, 64);
                contrib[h] += __shfl_xor(contrib[h], 32, 64);
            }
            s_part[w][q][lt * 16 + c] = contrib[q];
        }
        __syncthreads();                                     // B2

        // ---- combine wave partials -> s_att4 (f32, masked = -1e30) ----
        if (t < 256){
            int h = t >> 6, l = t & 63, gl = cch * 64 + l;
            if (gl < Ln){
                float a = 0.f;
                #pragma unroll
                for (int w2 = 0; w2 < 8; ++w2) a += s_part[w2][h][l];
                s_att4[gl * 4 + h] = (s_mask[gl] > 0.5f) ? a : -1.0e30f;
            }
        }
        // next B1 orders combine/stage vs next MFMA
    }
    __syncthreads();

    // ---- softmax over l (waves 0-3, one per head; f32 end-to-end) ----
    if (t < 256){
        const int h = t >> 6, sl = t & 63;
        float v[4]; float mx = -FLT_MAX;
        #pragma unroll
        for (int i = 0; i < 4; ++i){
            int l = sl + i * 64;
            v[i] = (l < Ln) ? s_att4[l * 4 + h] : -3.0e38f;
            mx = fmaxf(mx, v[i]);
        }
        for (int s = 32; s; s >>= 1) mx = fmaxf(mx, __shfl_xor(mx, s, 64));
        float e[4]; float sum = 0.f;
        #pragma unroll
        for (int i = 0; i < 4; ++i){
            int l = sl + i * 64;
            e[i] = (l < Ln) ? __expf(v[i] - mx) : 0.f;
            sum += e[i];
        }
        for (int s = 32; s; s >>= 1) sum += __shfl_xor(sum, s, 64);
        float inv = 1.f / sum;
        #pragma unroll
        for (int i = 0; i < 4; ++i){
            int l = sl + i * 64;
            if (l < Ln) s_att4[l * 4 + h] = e[i] * inv;
        }
    }
    __syncthreads();     // after this, chunk-phase views (s_x, s_part) are dead

    // ---- pooling: stream input (L2/L3-hot), 16 row-groups into overlaid s_scr ----
    {
        const int eg = t & 31, r = t >> 5;       // r = 0..15
        const float* xin = inp + (size_t)b * (Ln * En);
        f32x4 a0 = {0.f,0.f,0.f,0.f}, a1 = a0, a2 = a0, a3 = a0;
        for (int i = 0; i < 13; ++i){
            int l = i * 16 + r;
            if (l < Ln){
                f32x4 xv = *(const f32x4*)&xin[l * En + eg * 4];
                f32x4 w4 = *(const f32x4*)&s_att4[l * 4];
                a0 += xv * w4[0];
                a1 += xv * w4[1];
                a2 += xv * w4[2];
                a3 += xv * w4[3];
            }
        }
        *(f32x4*)&s_scr[r][0 * 128 + eg * 4] = a0;
        *(f32x4*)&s_scr[r][1 * 128 + eg * 4] = a1;
        *(f32x4*)&s_scr[r][2 * 128 + eg * 4] = a2;
        *(f32x4*)&s_scr[r][3 * 128 + eg * 4] = a3;
    }
    __syncthreads();

    // ---- final reduce over 16 row-groups -> pooled bf16 (flat h*128+e) ----
    {
        float sum = 0.f;
        #pragma unroll
        for (int r2 = 0; r2 < 16; ++r2) sum += s_scr[r2][t];
        slot[t] = f2bf(sum);
    }
}

// ================= K3: out = pooled @ Wout (MFMA) ===================================
__global__ __launch_bounds__(256) void sap_out(
    const void* __restrict__ ws, float* __restrict__ out)
{
    const unsigned short* wt = (const unsigned short*)((const char*)ws + WS_WOUTT);
    const int t = threadIdx.x, lane = t & 63, w = t >> 6;
    const int c = lane & 15, q = lane >> 4;
    const int b0 = blockIdx.x * 16;
    const int e0 = (blockIdx.y * 4 + w) * 16;

    const unsigned short* pslot =
        (const unsigned short*)((const char*)ws + WS_ATTPOOL + (size_t)(b0 + c) * SLOT);

    f32x4 acc = {0.f, 0.f, 0.f, 0.f};
    #pragma unroll 4
    for (int ks = 0; ks < 16; ++ks){
        bf16x8 afr = *(const bf16x8*)&pslot[ks * 32 + q * 8];
        bf16x8 bfr = *(const bf16x8*)&wt[(e0 + c) * 512 + ks * 32 + q * 8];
        acc = __builtin_amdgcn_mfma_f32_16x16x32_bf16(afr, bfr, acc, 0, 0, 0);
    }
    #pragma unroll
    for (int v = 0; v < 4; ++v)
        out[(size_t)(b0 + q * 4 + v) * En + e0 + c] = acc[v];
}

// ================= fallback (round-2 monolith) if ws ever shrinks ===================
__global__ __launch_bounds__(512, 4) void sap_fused_v2(
    const float* __restrict__ inp, const void* __restrict__ maskp,
    const float* __restrict__ pos, const float* __restrict__ W1,
    const float* __restrict__ W2, const float* __restrict__ Wout,
    float* __restrict__ out)
{
#define LP 208
    __shared__ unsigned short s_xp [LP * 128];
    __shared__ float s_att [4 * LP];
    __shared__ float s_mask[LP];
    __shared__ float s_pool[512];
    __shared__ float s_red [512];
    __shared__ int   s_flag;

    const int t = threadIdx.x;
    const int b = blockIdx.x;
    const int lane = t & 63, w = t >> 6;
    const int c = lane & 15, q = lane >> 4;

    if (t == 0){
        const unsigned* mw = (const unsigned*)maskp;
        int fi = 1, ff = 1;
        for (int i = 0; i < 64; ++i){
            unsigned word = mw[i];
            if (word > 1u) fi = 0;
            if (word != 0u && word != 0x3F800000u) ff = 0;
        }
        s_flag = fi ? 0 : (ff ? 2 : 1);
    }
    bf16x8 af[4];
    {
        const int arow = w * 16 + c;
        #pragma unroll
        for (int ks = 0; ks < 4; ++ks)
            #pragma unroll
            for (int j = 0; j < 8; ++j)
                af[ks][j] = (short)f2bf(W1[(ks * 32 + q * 8 + j) * An + arow]);
    }
    float w2a[4][4];
    #pragma unroll
    for (int v = 0; v < 4; ++v){
        float4 wv = *(const float4*)&W2[(w * 16 + q * 4 + v) * Hn];
        w2a[v][0] = wv.x; w2a[v][1] = wv.y; w2a[v][2] = wv.z; w2a[v][3] = wv.w;
    }
    __syncthreads();
    const int flag = s_flag;
    for (int l = t; l < LP; l += 512){
        float m = 0.f;
        if (l < Ln){
            int mv;
            if (flag == 0)      mv = ((const int*)maskp)[b * Ln + l] != 0;
            else if (flag == 1) mv = ((const unsigned char*)maskp)[b * Ln + l] != 0;
            else                mv = ((const float*)maskp)[b * Ln + l] != 0.f;
            m = mv ? 1.f : 0.f;
        }
        s_mask[l] = m;
    }
    for (int i = t; i < 4 * LP; i += 512) s_att[i] = 0.f;
    __syncthreads();
    {
        const float4* in4 = (const float4*)(inp + (size_t)b * (Ln * En));
        const float4* p4  = (const float4*)pos;
        #pragma unroll
        for (int it = 0; it < 13; ++it){
            int idx = it * 512 + t;
            int l = idx >> 5;
            int k = (idx & 31) * 4;
            uint2 val;
            if (idx < 6400){
                float m = s_mask[l];
                float4 a = in4[idx];
                float4 p = p4[idx];
                val = make_uint2((unsigned)f2bf(a.x*m+p.x) | ((unsigned)f2bf(a.y*m+p.y) << 16),
                                 (unsigned)f2bf(a.z*m+p.z) | ((unsigned)f2bf(a.w*m+p.w) << 16));
            } else val = make_uint2(0u, 0u);
            *(uint2*)&s_xp[swz(l, k)] = val;
        }
    }
    __syncthreads();
    for (int lt = 0; lt < 13; ++lt){
        int brow = lt * 16 + c;
        bf16x8 bfr[4];
        #pragma unroll
        for (int ks = 0; ks < 4; ++ks){
            int g = (ks * 4 + q) ^ c;
            bfr[ks] = *(bf16x8*)&s_xp[brow * 128 + (g << 3)];
        }
        f32x4 acc = {0.f, 0.f, 0.f, 0.f};
        #pragma unroll
        for (int ks = 0; ks < 4; ++ks)
            acc = __builtin_amdgcn_mfma_f32_16x16x32_bf16(af[ks], bfr[ks], acc, 0, 0, 0);
        float hv[4];
        #pragma unroll
        for (int v = 0; v < 4; ++v) hv[v] = tanh_fast(acc[v]);
        #pragma unroll
        for (int h = 0; h < 4; ++h){
            float contrib = hv[0]*w2a[0][h] + hv[1]*w2a[1][h] + hv[2]*w2a[2][h] + hv[3]*w2a[3][h];
            contrib += __shfl_xor(contrib, 16, 64);
            contrib += __shfl_xor(contrib, 32, 64);
            if (lane < 16) atomicAdd(&s_att[h * LP + lt * 16 + lane], contrib);
        }
    }
    __syncthreads();
    if (t < 256){
        const int sl = t & 63, h = t >> 6;
        float v[4]; bool ok[4]; float mx = -FLT_MAX;
        #pragma unroll
        for (int i = 0; i < 4; ++i){
            int l = sl + i * 64;
            ok[i] = (l < Ln) && (s_mask[l] > 0.5f);
            v[i]  = ok[i] ? s_att[h * LP + l] : -FLT_MAX;
            mx = fmaxf(mx, v[i]);
        }
        for (int s = 32; s; s >>= 1) mx = fmaxf(mx, __shfl_xor(mx, s, 64));
        float e[4]; float sum = 0.f;
        #pragma unroll
        for (int i = 0; i < 4; ++i){ e[i] = ok[i] ? __expf(v[i]-mx) : 0.f; sum += e[i]; }
        for (int s = 32; s; s >>= 1) sum += __shfl_xor(sum, s, 64);
        float inv = 1.f / sum;
        #pragma unroll
        for (int i = 0; i < 4; ++i){ int l = sl + i*64; if (l < LP) s_att[h*LP+l] = e[i]*inv; }
    }
    __syncthreads();
    {
        int h = t >> 7, e = t & 127;
        float acc = 0.f;
        #pragma unroll 4
        for (int l = 0; l < Ln; ++l){
            float xv = bf2f(s_xp[swz(l, e)]) - pos[l * En + e];
            acc += s_att[h * LP + l] * xv;
        }
        s_pool[h * En + e] = acc;
    }
    __syncthreads();
    {
        int qt = t >> 7, e = t & 127;
        float acc = 0.f;
        const float* wo = Wout + (size_t)(qt * 128) * En + e;
        #pragma unroll 4
        for (int i = 0; i < 128; ++i)
            acc += s_pool[qt * 128 + i] * wo[(size_t)i * En];
        s_red[t] = acc;
    }
    __syncthreads();
    if (t < 128)
        out[(size_t)b * En + t] = s_red[t] + s_red[t + 128] + s_red[t + 256] + s_red[t + 384];
#undef LP
}

extern "C" void kernel_launch(void* const* d_in, const int* in_sizes, int n_in,
                              void* d_out, int out_size, void* d_ws, size_t ws_size,
                              hipStream_t stream)
{
    const float* inp  = (const float*)d_in[0];
    const void*  mask = d_in[1];
    const float* pos  = (const float*)d_in[2];
    const float* W1   = (const float*)d_in[3];
    const float* W2   = (const float*)d_in[4];
    const float* Wout = (const float*)d_in[5];
    float* out = (float*)d_out;

    if (ws_size >= WS_NEEDED){
        sap_prep<<<170, 256, 0, stream>>>(pos, W1, Wout, d_ws);
        sap_att10<<<Bn, 512, 0, stream>>>(inp, mask, W2, d_ws);
        sap_out<<<dim3(64, 2), 256, 0, stream>>>(d_ws, out);
    } else {
        sap_fused_v2<<<Bn, 512, 0, stream>>>(inp, mask, pos, W1, W2, Wout, out);
    }
}